// Round 7
// baseline (458.630 us; speedup 1.0000x reference)
//
#include <hip/hip_runtime.h>

#define N_NODES 50000
#define N_EDGES 800000
#define D 128
#define NBKT ((N_NODES + 255) / 256)   // 196 buckets of 256 nodes
#define EPB 2048                       // edges per k_part block
#define LDA 136                        // LDS row stride in ushorts (128 + 8 pad)

typedef unsigned short u16;
typedef unsigned int   u32;
typedef short bf16x8 __attribute__((ext_vector_type(8)));
typedef float f32x16 __attribute__((ext_vector_type(16)));

// f32 -> bf16 (round-to-nearest-even)
__device__ __forceinline__ u16 f2b(float x) {
    union { float f; u32 u; } c; c.f = x;
    u32 r = c.u + 0x7FFFu + ((c.u >> 16) & 1u);
    return (u16)(r >> 16);
}
__device__ __forceinline__ float b2f(u16 u) {
    union { u32 u; float f; } c; c.u = ((u32)u) << 16;
    return c.f;
}

// ---------------------------------------------------------------------------
// B1: bucket histogram (bucket = dst>>8). LDS-staged.
// ---------------------------------------------------------------------------
__global__ __launch_bounds__(256) void k_bhist(const int* __restrict__ dst,
                                               int* __restrict__ gbh) {
    __shared__ int h[NBKT];
    for (int t = threadIdx.x; t < NBKT; t += 256) h[t] = 0;
    __syncthreads();
    int base = blockIdx.x * 1024;
#pragma unroll
    for (int j = 0; j < 4; ++j) {
        int e = base + j * 256 + (int)threadIdx.x;
        if (e < N_EDGES) atomicAdd(&h[dst[e] >> 8], 1);
    }
    __syncthreads();
    for (int t = threadIdx.x; t < NBKT; t += 256)
        if (h[t]) atomicAdd(&gbh[t], h[t]);
}

// ---------------------------------------------------------------------------
// B2: scan 196 bucket totals -> bucket_off[NBKT+1]; also row_off[N]=E.
// ---------------------------------------------------------------------------
__global__ __launch_bounds__(256) void k_bscan(const int* __restrict__ gbh,
                                               int* __restrict__ boff,
                                               int* __restrict__ row_off) {
    __shared__ int s[256];
    int v = ((int)threadIdx.x < NBKT) ? gbh[threadIdx.x] : 0;
    s[threadIdx.x] = v;
    __syncthreads();
#pragma unroll
    for (int off = 1; off < 256; off <<= 1) {
        int t = (threadIdx.x >= (unsigned)off) ? s[threadIdx.x - off] : 0;
        __syncthreads();
        s[threadIdx.x] += t;
        __syncthreads();
    }
    if ((int)threadIdx.x < NBKT) boff[threadIdx.x] = s[threadIdx.x] - v;
    if (threadIdx.x == 0) { boff[NBKT] = N_EDGES; row_off[N_NODES] = N_EDGES; }
}

// ---------------------------------------------------------------------------
// B3: partition edges into bucket-contiguous ebuf (chunk reservation).
// ---------------------------------------------------------------------------
__global__ __launch_bounds__(256) void k_part(const int* __restrict__ src,
                                              const int* __restrict__ dst,
                                              const int* __restrict__ boff,
                                              int* __restrict__ gbfill,
                                              u32* __restrict__ ebuf) {
    __shared__ u16 ls[EPB], ld_[EPB];
    __shared__ int hist[NBKT], lcnt[NBKT], basev[NBKT];
    const int e0 = blockIdx.x * EPB;
    for (int t = threadIdx.x; t < NBKT; t += 256) { hist[t] = 0; lcnt[t] = 0; }
    __syncthreads();
#pragma unroll
    for (int j = 0; j < EPB / 256; ++j) {
        int t = j * 256 + (int)threadIdx.x;
        int e = e0 + t;
        if (e < N_EDGES) {
            int d = dst[e];
            ls[t] = (u16)src[e];
            ld_[t] = (u16)d;
            atomicAdd(&hist[d >> 8], 1);
        }
    }
    __syncthreads();
    for (int t = threadIdx.x; t < NBKT; t += 256)
        basev[t] = boff[t] + (hist[t] ? atomicAdd(&gbfill[t], hist[t]) : 0);
    __syncthreads();
#pragma unroll
    for (int j = 0; j < EPB / 256; ++j) {
        int t = j * 256 + (int)threadIdx.x;
        int e = e0 + t;
        if (e < N_EDGES) {
            int d = (int)ld_[t];
            int b = d >> 8;
            int o = atomicAdd(&lcnt[b], 1);
            ebuf[basev[b] + o] = (u32)ls[t] | ((u32)(d & 255) << 16);
        }
    }
}

// ---------------------------------------------------------------------------
// B4: per-bucket build: LDS degree hist + scan -> row_off/rcp, csr fill (u16).
// ---------------------------------------------------------------------------
__global__ __launch_bounds__(256) void k_build(const u32* __restrict__ ebuf,
                                               const int* __restrict__ boff,
                                               int* __restrict__ row_off,
                                               float* __restrict__ rcp,
                                               u16* __restrict__ csr) {
    __shared__ int dcnt[256], fcnt[256], sdata[256];
    const int b = blockIdx.x;
    const int beg = boff[b], end = boff[b + 1];
    dcnt[threadIdx.x] = 0;
    fcnt[threadIdx.x] = 0;
    __syncthreads();
    for (int j = beg + (int)threadIdx.x; j < end; j += 256)
        atomicAdd(&dcnt[(ebuf[j] >> 16) & 255], 1);
    __syncthreads();
    int v = dcnt[threadIdx.x];
    sdata[threadIdx.x] = v;
    __syncthreads();
#pragma unroll
    for (int off = 1; off < 256; off <<= 1) {
        int t = (threadIdx.x >= (unsigned)off) ? sdata[threadIdx.x - off] : 0;
        __syncthreads();
        sdata[threadIdx.x] += t;
        __syncthreads();
    }
    int node = (b << 8) + (int)threadIdx.x;
    if (node < N_NODES) {
        row_off[node] = beg + sdata[threadIdx.x] - v;
        rcp[node] = 1.0f / (float)max(v, 1);
    }
    for (int j = beg + (int)threadIdx.x; j < end; j += 256) {
        u32 u = ebuf[j];
        int ln = (u >> 16) & 255;
        int o = atomicAdd(&fcnt[ln], 1);
        csr[beg + (sdata[ln] - dcnt[ln]) + o] = (u16)(u & 0xFFFFu);
    }
}

// ---------------------------------------------------------------------------
// K4: cast features f32 -> bf16 (8 elems/thread)
// ---------------------------------------------------------------------------
__global__ __launch_bounds__(256) void k_cast(const float* __restrict__ f,
                                              u16* __restrict__ o) {
    int idx = blockIdx.x * 256 + (int)threadIdx.x;
    if (idx < N_NODES * (D / 8)) {
        const float4* fp = (const float4*)(f + (size_t)idx * 8);
        float4 a = fp[0], b = fp[1];
        uint4 p;
        p.x = (u32)f2b(a.x) | ((u32)f2b(a.y) << 16);
        p.y = (u32)f2b(a.z) | ((u32)f2b(a.w) << 16);
        p.z = (u32)f2b(b.x) | ((u32)f2b(b.y) << 16);
        p.w = (u32)f2b(b.z) | ((u32)f2b(b.w) << 16);
        ((uint4*)o)[idx] = p;
    }
}

// ---------------------------------------------------------------------------
// K5: transpose+cast the 6 weight matrices: W[k][n] f32 -> Wt[n][k] bf16
// ---------------------------------------------------------------------------
__global__ __launch_bounds__(256) void k_prepw(
        const float* __restrict__ w0, const float* __restrict__ w1,
        const float* __restrict__ w2, const float* __restrict__ w3,
        const float* __restrict__ w4, const float* __restrict__ w5,
        u16* __restrict__ wt) {
    const float* W;
    switch (blockIdx.y) {
        case 0: W = w0; break; case 1: W = w1; break; case 2: W = w2; break;
        case 3: W = w3; break; case 4: W = w4; break; default: W = w5; break;
    }
    u16* out = wt + (size_t)blockIdx.y * D * D;
    int k0 = blockIdx.x * 32;
    __shared__ float s[32][129];
    for (int t = threadIdx.x; t < 32 * 32; t += 256) {
        int r = t >> 5, c4 = t & 31;
        float4 v = ((const float4*)&W[(size_t)(k0 + r) * D])[c4];
        s[r][c4 * 4 + 0] = v.x; s[r][c4 * 4 + 1] = v.y;
        s[r][c4 * 4 + 2] = v.z; s[r][c4 * 4 + 3] = v.w;
    }
    __syncthreads();
    for (int t = threadIdx.x; t < 512; t += 256) {
        int n = t >> 2, g = t & 3;
        uint4 p;
        p.x = (u32)f2b(s[g * 8 + 0][n]) | ((u32)f2b(s[g * 8 + 1][n]) << 16);
        p.y = (u32)f2b(s[g * 8 + 2][n]) | ((u32)f2b(s[g * 8 + 3][n]) << 16);
        p.z = (u32)f2b(s[g * 8 + 4][n]) | ((u32)f2b(s[g * 8 + 5][n]) << 16);
        p.w = (u32)f2b(s[g * 8 + 6][n]) | ((u32)f2b(s[g * 8 + 7][n]) << 16);
        *(uint4*)&out[(size_t)n * D + k0 + g * 8] = p;
    }
}

// ---------------------------------------------------------------------------
// K6: MFMA GEMM (R5-measured variant): out = A(bf16) @ W(bf16), f32 acc.
// Block 256 thr = 4 waves in 2x2; block tile M=64 x N=128; full K=128 in LDS.
// ---------------------------------------------------------------------------
__global__ __launch_bounds__(256) void k_gemm(
        const u16* __restrict__ A, const u16* __restrict__ Wt_self,
        const u16* __restrict__ Wt_neigh, const float* __restrict__ bias,
        u16* __restrict__ hs, u16* __restrict__ hn) {
    const bool is_self = (blockIdx.y == 0);
    const u16* __restrict__ Wt = is_self ? Wt_self : Wt_neigh;
    u16* __restrict__ outp = is_self ? hs : hn;
    const int row0 = blockIdx.x * 64;

    __shared__ u16 As[64 * LDA];
    __shared__ u16 Ws[128 * LDA];

    const int tid = (int)threadIdx.x;
    for (int t = tid; t < 1024; t += 256) {        // 64 rows x 16 chunks
        int r = t >> 4, c = t & 15;
        int row = row0 + r; if (row >= N_NODES) row = N_NODES - 1;
        *(float4*)&As[r * LDA + c * 8] = ((const float4*)&A[(size_t)row * D])[c];
    }
    for (int t = tid; t < 2048; t += 256) {        // 128 rows x 16 chunks
        int r = t >> 4, c = t & 15;
        *(float4*)&Ws[r * LDA + c * 8] = ((const float4*)&Wt[(size_t)r * D])[c];
    }
    __syncthreads();

    const int lane = tid & 63;
    const int wave = tid >> 6;
    const int wm = wave & 1;
    const int wn = wave >> 1;
    const int m  = lane & 31;
    const int kh = lane >> 5;

    f32x16 acc0, acc1;
#pragma unroll
    for (int i = 0; i < 16; ++i) { acc0[i] = 0.0f; acc1[i] = 0.0f; }

    const u16* ap  = &As[(wm * 32 + m) * LDA + kh * 8];
    const u16* bp0 = &Ws[(wn * 64 + m) * LDA + kh * 8];
    const u16* bp1 = bp0 + 32 * LDA;
#pragma unroll
    for (int kk = 0; kk < 8; ++kk) {
        bf16x8 a  = *(const bf16x8*)(ap  + kk * 16);
        bf16x8 b0 = *(const bf16x8*)(bp0 + kk * 16);
        bf16x8 b1 = *(const bf16x8*)(bp1 + kk * 16);
        acc0 = __builtin_amdgcn_mfma_f32_32x32x16_bf16(a, b0, acc0, 0, 0, 0);
        acc1 = __builtin_amdgcn_mfma_f32_32x32x16_bf16(a, b1, acc1, 0, 0, 0);
    }

    const int c0 = wn * 64 + m;
    const int c1 = c0 + 32;
    const float b0v = is_self ? bias[c0] : 0.0f;
    const float b1v = is_self ? bias[c1] : 0.0f;
#pragma unroll
    for (int r = 0; r < 16; ++r) {
        int rowl = (r & 3) + 8 * (r >> 2) + 4 * kh;
        int grow = row0 + wm * 32 + rowl;
        if (grow < N_NODES) {
            outp[(size_t)grow * D + c0] = f2b(acc0[r] + b0v);
            outp[(size_t)grow * D + c1] = f2b(acc1[r] + b1v);
        }
    }
}

// ---------------------------------------------------------------------------
// K7: column-sliced aggregate. slice = blockIdx.x & 3 (32 cols = 3.2 MB of hn
// -> L2-resident per XCD under round-robin block->XCD mapping). Wave/node;
// 4 neighbor groups x 16 lanes x 4B (one 64B line per gather). Neighbor
// summation order identical to previous version -> bitwise-same output.
// ---------------------------------------------------------------------------
__global__ __launch_bounds__(256) void k_agg(
        const u16* __restrict__ hs, const u16* __restrict__ hn,
        const int* __restrict__ row_off, const u16* __restrict__ csr,
        const float* __restrict__ rcp, void* __restrict__ outp, int final_f32) {
    const int bx = (int)blockIdx.x;
    const int slice = bx & 3;                      // low bits -> XCD-pinned
    const int v = (bx >> 2) * 4 + (int)(threadIdx.x >> 6);
    if (v >= N_NODES) return;
    const int lane = (int)threadIdx.x & 63;
    const int g = lane >> 4, cl = lane & 15;
    const int colb = slice * 32 + cl * 2;          // 2 cols per lane
    const int beg = row_off[v], end = row_off[v + 1];

    float a0 = 0.0f, a1 = 0.0f;
    int j = beg + g;
    for (; j + 4 < end; j += 8) {
        int u0 = csr[j], u1 = csr[j + 4];
        u32 x0 = *(const u32*)&hn[(size_t)u0 * D + colb];
        u32 x1 = *(const u32*)&hn[(size_t)u1 * D + colb];
        a0 += b2f((u16)(x0 & 0xFFFFu)) + b2f((u16)(x1 & 0xFFFFu));
        a1 += b2f((u16)(x0 >> 16)) + b2f((u16)(x1 >> 16));
    }
    if (j < end) {
        int u0 = csr[j];
        u32 x0 = *(const u32*)&hn[(size_t)u0 * D + colb];
        a0 += b2f((u16)(x0 & 0xFFFFu));
        a1 += b2f((u16)(x0 >> 16));
    }
    a0 += __shfl_xor(a0, 16); a0 += __shfl_xor(a0, 32);
    a1 += __shfl_xor(a1, 16); a1 += __shfl_xor(a1, 32);

    if (lane < 16) {
        float r = rcp[v];
        u32 sv = *(const u32*)&hs[(size_t)v * D + colb];
        float o0 = fmaf(a0, r, b2f((u16)(sv & 0xFFFFu)));
        float o1 = fmaf(a1, r, b2f((u16)(sv >> 16)));
        if (!final_f32) {
            o0 = fmaxf(o0, 0.0f); o1 = fmaxf(o1, 0.0f);
            *(u32*)&((u16*)outp)[(size_t)v * D + colb] =
                (u32)f2b(o0) | ((u32)f2b(o1) << 16);
        } else {
            float2 p = {o0, o1};
            *(float2*)&((float*)outp)[(size_t)v * D + colb] = p;
        }
    }
}

// ---------------------------------------------------------------------------
extern "C" void kernel_launch(void* const* d_in, const int* in_sizes, int n_in,
                              void* d_out, int out_size, void* d_ws, size_t ws_size,
                              hipStream_t stream) {
    const float* features = (const float*)d_in[0];
    const int*   edge_src = (const int*)d_in[1];
    const int*   edge_dst = (const int*)d_in[2];
    const float* Wself[3] = {(const float*)d_in[3], (const float*)d_in[6], (const float*)d_in[9]};
    const float* Wngh[3]  = {(const float*)d_in[4], (const float*)d_in[7], (const float*)d_in[10]};
    const float* bias[3]  = {(const float*)d_in[5], (const float*)d_in[8], (const float*)d_in[11]};
    float* out = (float*)d_out;

    char* ws = (char*)d_ws;
    size_t off = 0;
    auto alloc = [&](size_t bytes) {
        char* p = ws + off;
        off += (bytes + 255) & ~(size_t)255;
        return p;
    };
    int*   gcnt    = (int*)alloc(2 * 256 * sizeof(int));   // gbh | gbfill
    int*   gbh     = gcnt;
    int*   gbfill  = gcnt + 256;
    int*   boff    = (int*)alloc((NBKT + 1) * sizeof(int));
    int*   row_off = (int*)alloc((N_NODES + 1) * sizeof(int));
    float* rcp     = (float*)alloc(N_NODES * sizeof(float));
    u32*   ebuf    = (u32*)alloc((size_t)N_EDGES * sizeof(u32));
    u16*   csr     = (u16*)alloc((size_t)N_EDGES * sizeof(u16));
    u16*   hs      = (u16*)alloc((size_t)N_NODES * D * sizeof(u16));
    u16*   hn      = (u16*)alloc((size_t)N_NODES * D * sizeof(u16));
    u16*   hb0     = (u16*)alloc((size_t)N_NODES * D * sizeof(u16));
    u16*   hb1     = (u16*)alloc((size_t)N_NODES * D * sizeof(u16));
    u16*   wt      = (u16*)alloc((size_t)6 * D * D * sizeof(u16));

    hipMemsetAsync(gcnt, 0, 2 * 256 * sizeof(int), stream);

    // CSR build (bucketed)
    k_bhist<<<(N_EDGES + 1023) / 1024, 256, 0, stream>>>(edge_dst, gbh);
    k_bscan<<<1, 256, 0, stream>>>(gbh, boff, row_off);
    k_part<<<(N_EDGES + EPB - 1) / EPB, 256, 0, stream>>>(edge_src, edge_dst, boff, gbfill, ebuf);
    k_build<<<NBKT, 256, 0, stream>>>(ebuf, boff, row_off, rcp, csr);

    // bf16 prep
    k_cast<<<(N_NODES * (D / 8) + 255) / 256, 256, 0, stream>>>(features, hb0);
    k_prepw<<<dim3(4, 6), 256, 0, stream>>>(Wself[0], Wngh[0], Wself[1], Wngh[1],
                                            Wself[2], Wngh[2], wt);

    const int gemm_gx = (N_NODES + 63) / 64;
    const int agg_gx  = ((N_NODES + 3) / 4) * 4;   // node-quads x 4 slices
    const size_t WSZ = (size_t)D * D;

    // layer 0: hb0 -> hb1 (relu)
    k_gemm<<<dim3(gemm_gx, 2), 256, 0, stream>>>(hb0, wt + 0 * WSZ, wt + 1 * WSZ, bias[0], hs, hn);
    k_agg<<<agg_gx, 256, 0, stream>>>(hs, hn, row_off, csr, rcp, hb1, 0);
    // layer 1: hb1 -> hb0 (relu)
    k_gemm<<<dim3(gemm_gx, 2), 256, 0, stream>>>(hb1, wt + 2 * WSZ, wt + 3 * WSZ, bias[1], hs, hn);
    k_agg<<<agg_gx, 256, 0, stream>>>(hs, hn, row_off, csr, rcp, hb0, 0);
    // layer 2: hb0 -> out (f32, no act)
    k_gemm<<<dim3(gemm_gx, 2), 256, 0, stream>>>(hb0, wt + 4 * WSZ, wt + 5 * WSZ, bias[2], hs, hn);
    k_agg<<<agg_gx, 256, 0, stream>>>(hs, hn, row_off, csr, rcp, out, 1);
}

// Round 8
// 323.185 us; speedup vs baseline: 1.4191x; 1.4191x over previous
//
#include <hip/hip_runtime.h>

#define N_NODES 50000
#define N_EDGES 800000
#define D 128
#define NBKT ((N_NODES + 255) / 256)   // 196 buckets of 256 nodes
#define EPB 2048                       // edges per k_part block

typedef unsigned short u16;
typedef unsigned int   u32;
typedef short bf16x8 __attribute__((ext_vector_type(8)));
typedef float f32x16 __attribute__((ext_vector_type(16)));

// f32 -> bf16 (round-to-nearest-even)
__device__ __forceinline__ u16 f2b(float x) {
    union { float f; u32 u; } c; c.f = x;
    u32 r = c.u + 0x7FFFu + ((c.u >> 16) & 1u);
    return (u16)(r >> 16);
}
__device__ __forceinline__ float b2f(u16 u) {
    union { u32 u; float f; } c; c.u = ((u32)u) << 16;
    return c.f;
}

// ---------------------------------------------------------------------------
// B1: bucket histogram (bucket = dst>>8). LDS-staged.
// ---------------------------------------------------------------------------
__global__ __launch_bounds__(256) void k_bhist(const int* __restrict__ dst,
                                               int* __restrict__ gbh) {
    __shared__ int h[NBKT];
    for (int t = threadIdx.x; t < NBKT; t += 256) h[t] = 0;
    __syncthreads();
    int base = blockIdx.x * 1024;
#pragma unroll
    for (int j = 0; j < 4; ++j) {
        int e = base + j * 256 + (int)threadIdx.x;
        if (e < N_EDGES) atomicAdd(&h[dst[e] >> 8], 1);
    }
    __syncthreads();
    for (int t = threadIdx.x; t < NBKT; t += 256)
        if (h[t]) atomicAdd(&gbh[t], h[t]);
}

// ---------------------------------------------------------------------------
// B2: scan 196 bucket totals -> bucket_off[NBKT+1]; also row_off[N]=E.
// ---------------------------------------------------------------------------
__global__ __launch_bounds__(256) void k_bscan(const int* __restrict__ gbh,
                                               int* __restrict__ boff,
                                               int* __restrict__ row_off) {
    __shared__ int s[256];
    int v = ((int)threadIdx.x < NBKT) ? gbh[threadIdx.x] : 0;
    s[threadIdx.x] = v;
    __syncthreads();
#pragma unroll
    for (int off = 1; off < 256; off <<= 1) {
        int t = (threadIdx.x >= (unsigned)off) ? s[threadIdx.x - off] : 0;
        __syncthreads();
        s[threadIdx.x] += t;
        __syncthreads();
    }
    if ((int)threadIdx.x < NBKT) boff[threadIdx.x] = s[threadIdx.x] - v;
    if (threadIdx.x == 0) { boff[NBKT] = N_EDGES; row_off[N_NODES] = N_EDGES; }
}

// ---------------------------------------------------------------------------
// B3: partition edges into bucket-contiguous ebuf (chunk reservation).
// ---------------------------------------------------------------------------
__global__ __launch_bounds__(256) void k_part(const int* __restrict__ src,
                                              const int* __restrict__ dst,
                                              const int* __restrict__ boff,
                                              int* __restrict__ gbfill,
                                              u32* __restrict__ ebuf) {
    __shared__ u16 ls[EPB], ld_[EPB];
    __shared__ int hist[NBKT], lcnt[NBKT], basev[NBKT];
    const int e0 = blockIdx.x * EPB;
    for (int t = threadIdx.x; t < NBKT; t += 256) { hist[t] = 0; lcnt[t] = 0; }
    __syncthreads();
#pragma unroll
    for (int j = 0; j < EPB / 256; ++j) {
        int t = j * 256 + (int)threadIdx.x;
        int e = e0 + t;
        if (e < N_EDGES) {
            int d = dst[e];
            ls[t] = (u16)src[e];
            ld_[t] = (u16)d;
            atomicAdd(&hist[d >> 8], 1);
        }
    }
    __syncthreads();
    for (int t = threadIdx.x; t < NBKT; t += 256)
        basev[t] = boff[t] + (hist[t] ? atomicAdd(&gbfill[t], hist[t]) : 0);
    __syncthreads();
#pragma unroll
    for (int j = 0; j < EPB / 256; ++j) {
        int t = j * 256 + (int)threadIdx.x;
        int e = e0 + t;
        if (e < N_EDGES) {
            int d = (int)ld_[t];
            int b = d >> 8;
            int o = atomicAdd(&lcnt[b], 1);
            ebuf[basev[b] + o] = (u32)ls[t] | ((u32)(d & 255) << 16);
        }
    }
}

// ---------------------------------------------------------------------------
// B4: per-bucket build: LDS degree hist + scan -> row_off/rcp, csr fill (u16).
// ---------------------------------------------------------------------------
__global__ __launch_bounds__(256) void k_build(const u32* __restrict__ ebuf,
                                               const int* __restrict__ boff,
                                               int* __restrict__ row_off,
                                               float* __restrict__ rcp,
                                               u16* __restrict__ csr) {
    __shared__ int dcnt[256], fcnt[256], sdata[256];
    const int b = blockIdx.x;
    const int beg = boff[b], end = boff[b + 1];
    dcnt[threadIdx.x] = 0;
    fcnt[threadIdx.x] = 0;
    __syncthreads();
    for (int j = beg + (int)threadIdx.x; j < end; j += 256)
        atomicAdd(&dcnt[(ebuf[j] >> 16) & 255], 1);
    __syncthreads();
    int v = dcnt[threadIdx.x];
    sdata[threadIdx.x] = v;
    __syncthreads();
#pragma unroll
    for (int off = 1; off < 256; off <<= 1) {
        int t = (threadIdx.x >= (unsigned)off) ? sdata[threadIdx.x - off] : 0;
        __syncthreads();
        sdata[threadIdx.x] += t;
        __syncthreads();
    }
    int node = (b << 8) + (int)threadIdx.x;
    if (node < N_NODES) {
        row_off[node] = beg + sdata[threadIdx.x] - v;
        rcp[node] = 1.0f / (float)max(v, 1);
    }
    for (int j = beg + (int)threadIdx.x; j < end; j += 256) {
        u32 u = ebuf[j];
        int ln = (u >> 16) & 255;
        int o = atomicAdd(&fcnt[ln], 1);
        csr[beg + (sdata[ln] - dcnt[ln]) + o] = (u16)(u & 0xFFFFu);
    }
}

// ---------------------------------------------------------------------------
// K4: cast features f32 -> bf16 (8 elems/thread)
// ---------------------------------------------------------------------------
__global__ __launch_bounds__(256) void k_cast(const float* __restrict__ f,
                                              u16* __restrict__ o) {
    int idx = blockIdx.x * 256 + (int)threadIdx.x;
    if (idx < N_NODES * (D / 8)) {
        const float4* fp = (const float4*)(f + (size_t)idx * 8);
        float4 a = fp[0], b = fp[1];
        uint4 p;
        p.x = (u32)f2b(a.x) | ((u32)f2b(a.y) << 16);
        p.y = (u32)f2b(a.z) | ((u32)f2b(a.w) << 16);
        p.z = (u32)f2b(b.x) | ((u32)f2b(b.y) << 16);
        p.w = (u32)f2b(b.z) | ((u32)f2b(b.w) << 16);
        ((uint4*)o)[idx] = p;
    }
}

// ---------------------------------------------------------------------------
// K5: transpose+cast the 6 weight matrices: W[k][n] f32 -> Wt[n][k] bf16
// ---------------------------------------------------------------------------
__global__ __launch_bounds__(256) void k_prepw(
        const float* __restrict__ w0, const float* __restrict__ w1,
        const float* __restrict__ w2, const float* __restrict__ w3,
        const float* __restrict__ w4, const float* __restrict__ w5,
        u16* __restrict__ wt) {
    const float* W;
    switch (blockIdx.y) {
        case 0: W = w0; break; case 1: W = w1; break; case 2: W = w2; break;
        case 3: W = w3; break; case 4: W = w4; break; default: W = w5; break;
    }
    u16* out = wt + (size_t)blockIdx.y * D * D;
    int k0 = blockIdx.x * 32;
    __shared__ float s[32][129];
    for (int t = threadIdx.x; t < 32 * 32; t += 256) {
        int r = t >> 5, c4 = t & 31;
        float4 v = ((const float4*)&W[(size_t)(k0 + r) * D])[c4];
        s[r][c4 * 4 + 0] = v.x; s[r][c4 * 4 + 1] = v.y;
        s[r][c4 * 4 + 2] = v.z; s[r][c4 * 4 + 3] = v.w;
    }
    __syncthreads();
    for (int t = threadIdx.x; t < 512; t += 256) {
        int n = t >> 2, g = t & 3;
        uint4 p;
        p.x = (u32)f2b(s[g * 8 + 0][n]) | ((u32)f2b(s[g * 8 + 1][n]) << 16);
        p.y = (u32)f2b(s[g * 8 + 2][n]) | ((u32)f2b(s[g * 8 + 3][n]) << 16);
        p.z = (u32)f2b(s[g * 8 + 4][n]) | ((u32)f2b(s[g * 8 + 5][n]) << 16);
        p.w = (u32)f2b(s[g * 8 + 6][n]) | ((u32)f2b(s[g * 8 + 7][n]) << 16);
        *(uint4*)&out[(size_t)n * D + k0 + g * 8] = p;
    }
}

// ---------------------------------------------------------------------------
// K6: LDS-free MFMA GEMM: out = A(bf16) @ W(bf16), f32 acc, bf16 out.
// No __shared__, no barriers. W (32 KB) is L1-resident (same lines read by
// every block); A fragments preloaded per wave, streamed via L2.
// Block 256 thr = 4 waves in 2x2; block tile M=64 x N=128.
// Fragment & MFMA order identical to the R5 LDS version -> bitwise-same out.
// ---------------------------------------------------------------------------
__global__ __launch_bounds__(256) void k_gemm(
        const u16* __restrict__ A, const u16* __restrict__ Wt_self,
        const u16* __restrict__ Wt_neigh, const float* __restrict__ bias,
        u16* __restrict__ hs, u16* __restrict__ hn) {
    const bool is_self = (blockIdx.y == 0);
    const u16* __restrict__ Wt = is_self ? Wt_self : Wt_neigh;
    u16* __restrict__ outp = is_self ? hs : hn;
    const int row0 = blockIdx.x * 64;

    const int tid  = (int)threadIdx.x;
    const int lane = tid & 63;
    const int wave = tid >> 6;
    const int wm = wave & 1;    // row band (32 rows)
    const int wn = wave >> 1;   // col half (64 cols)
    const int m  = lane & 31;
    const int kh = lane >> 5;   // k-half within 16-chunk

    int arow = row0 + wm * 32 + m;
    if (arow >= N_NODES) arow = N_NODES - 1;   // clamp load; stores guarded

    const u16* ap  = &A[(size_t)arow * D + kh * 8];
    const u16* bp0 = &Wt[(size_t)(wn * 64 + m) * D + kh * 8];
    const u16* bp1 = bp0 + 32 * D;

    // preload all 8 A fragments (independent loads -> deep MLP)
    bf16x8 a[8];
#pragma unroll
    for (int kk = 0; kk < 8; ++kk) a[kk] = *(const bf16x8*)(ap + kk * 16);

    f32x16 acc0, acc1;
#pragma unroll
    for (int i = 0; i < 16; ++i) { acc0[i] = 0.0f; acc1[i] = 0.0f; }

#pragma unroll
    for (int kk = 0; kk < 8; ++kk) {
        bf16x8 b0 = *(const bf16x8*)(bp0 + kk * 16);
        bf16x8 b1 = *(const bf16x8*)(bp1 + kk * 16);
        acc0 = __builtin_amdgcn_mfma_f32_32x32x16_bf16(a[kk], b0, acc0, 0, 0, 0);
        acc1 = __builtin_amdgcn_mfma_f32_32x32x16_bf16(a[kk], b1, acc1, 0, 0, 0);
    }

    // epilogue: C/D layout: col = lane&31, row = (r&3) + 8*(r>>2) + 4*(lane>>5)
    const int c0 = wn * 64 + m;
    const int c1 = c0 + 32;
    const float b0v = is_self ? bias[c0] : 0.0f;
    const float b1v = is_self ? bias[c1] : 0.0f;
#pragma unroll
    for (int r = 0; r < 16; ++r) {
        int rowl = (r & 3) + 8 * (r >> 2) + 4 * kh;
        int grow = row0 + wm * 32 + rowl;
        if (grow < N_NODES) {
            outp[(size_t)grow * D + c0] = f2b(acc0[r] + b0v);
            outp[(size_t)grow * D + c1] = f2b(acc1[r] + b1v);
        }
    }
}

// ---------------------------------------------------------------------------
// K7: aggregate (R5-measured variant): out[v] = act(hs[v] + rcp[v]*sum hn[u]).
// One wave/node; quad q handles neighbor j=beg+q (4 nbrs/iter, unroll x2);
// 16 lanes x 16B (8 bf16) per neighbor row. f32 accumulate; shfl-xor reduce.
// ---------------------------------------------------------------------------
__global__ __launch_bounds__(256) void k_agg(
        const u16* __restrict__ hs, const u16* __restrict__ hn,
        const int* __restrict__ row_off, const u16* __restrict__ csr,
        const float* __restrict__ rcp, void* __restrict__ outp, int final_f32) {
    int v = blockIdx.x * 4 + (int)(threadIdx.x >> 6);
    if (v >= N_NODES) return;
    int lane = (int)threadIdx.x & 63;
    int q = lane >> 4, cl = lane & 15;
    int beg = row_off[v], end = row_off[v + 1];

    float ax[8];
#pragma unroll
    for (int i = 0; i < 8; ++i) ax[i] = 0.0f;

    int j = beg + q;
    for (; j + 4 < end; j += 8) {
        int u0 = csr[j], u1 = csr[j + 4];
        bf16x8 x0 = *(const bf16x8*)&hn[(size_t)u0 * D + cl * 8];
        bf16x8 x1 = *(const bf16x8*)&hn[(size_t)u1 * D + cl * 8];
#pragma unroll
        for (int i = 0; i < 8; ++i)
            ax[i] += b2f((u16)x0[i]) + b2f((u16)x1[i]);
    }
    if (j < end) {
        int u0 = csr[j];
        bf16x8 x0 = *(const bf16x8*)&hn[(size_t)u0 * D + cl * 8];
#pragma unroll
        for (int i = 0; i < 8; ++i) ax[i] += b2f((u16)x0[i]);
    }
#pragma unroll
    for (int i = 0; i < 8; ++i) {
        ax[i] += __shfl_xor(ax[i], 16);
        ax[i] += __shfl_xor(ax[i], 32);
    }
    if (lane < 16) {
        float r = rcp[v];
        bf16x8 sv = *(const bf16x8*)&hs[(size_t)v * D + cl * 8];
        float o[8];
#pragma unroll
        for (int i = 0; i < 8; ++i) o[i] = fmaf(ax[i], r, b2f((u16)sv[i]));
        if (!final_f32) {
#pragma unroll
            for (int i = 0; i < 8; ++i) o[i] = fmaxf(o[i], 0.0f);
            uint4 p;
            p.x = (u32)f2b(o[0]) | ((u32)f2b(o[1]) << 16);
            p.y = (u32)f2b(o[2]) | ((u32)f2b(o[3]) << 16);
            p.z = (u32)f2b(o[4]) | ((u32)f2b(o[5]) << 16);
            p.w = (u32)f2b(o[6]) | ((u32)f2b(o[7]) << 16);
            *(uint4*)&((u16*)outp)[(size_t)v * D + cl * 8] = p;
        } else {
            float* of = (float*)outp;
            float4 p0 = {o[0], o[1], o[2], o[3]};
            float4 p1 = {o[4], o[5], o[6], o[7]};
            ((float4*)&of[(size_t)v * D + cl * 8])[0] = p0;
            ((float4*)&of[(size_t)v * D + cl * 8])[1] = p1;
        }
    }
}

// ---------------------------------------------------------------------------
extern "C" void kernel_launch(void* const* d_in, const int* in_sizes, int n_in,
                              void* d_out, int out_size, void* d_ws, size_t ws_size,
                              hipStream_t stream) {
    const float* features = (const float*)d_in[0];
    const int*   edge_src = (const int*)d_in[1];
    const int*   edge_dst = (const int*)d_in[2];
    const float* Wself[3] = {(const float*)d_in[3], (const float*)d_in[6], (const float*)d_in[9]};
    const float* Wngh[3]  = {(const float*)d_in[4], (const float*)d_in[7], (const float*)d_in[10]};
    const float* bias[3]  = {(const float*)d_in[5], (const float*)d_in[8], (const float*)d_in[11]};
    float* out = (float*)d_out;

    char* ws = (char*)d_ws;
    size_t off = 0;
    auto alloc = [&](size_t bytes) {
        char* p = ws + off;
        off += (bytes + 255) & ~(size_t)255;
        return p;
    };
    int*   gcnt    = (int*)alloc(2 * 256 * sizeof(int));   // gbh | gbfill
    int*   gbh     = gcnt;
    int*   gbfill  = gcnt + 256;
    int*   boff    = (int*)alloc((NBKT + 1) * sizeof(int));
    int*   row_off = (int*)alloc((N_NODES + 1) * sizeof(int));
    float* rcp     = (float*)alloc(N_NODES * sizeof(float));
    u32*   ebuf    = (u32*)alloc((size_t)N_EDGES * sizeof(u32));
    u16*   csr     = (u16*)alloc((size_t)N_EDGES * sizeof(u16));
    u16*   hs      = (u16*)alloc((size_t)N_NODES * D * sizeof(u16));
    u16*   hn      = (u16*)alloc((size_t)N_NODES * D * sizeof(u16));
    u16*   hb0     = (u16*)alloc((size_t)N_NODES * D * sizeof(u16));
    u16*   hb1     = (u16*)alloc((size_t)N_NODES * D * sizeof(u16));
    u16*   wt      = (u16*)alloc((size_t)6 * D * D * sizeof(u16));

    hipMemsetAsync(gcnt, 0, 2 * 256 * sizeof(int), stream);

    // CSR build (bucketed)
    k_bhist<<<(N_EDGES + 1023) / 1024, 256, 0, stream>>>(edge_dst, gbh);
    k_bscan<<<1, 256, 0, stream>>>(gbh, boff, row_off);
    k_part<<<(N_EDGES + EPB - 1) / EPB, 256, 0, stream>>>(edge_src, edge_dst, boff, gbfill, ebuf);
    k_build<<<NBKT, 256, 0, stream>>>(ebuf, boff, row_off, rcp, csr);

    // bf16 prep
    k_cast<<<(N_NODES * (D / 8) + 255) / 256, 256, 0, stream>>>(features, hb0);
    k_prepw<<<dim3(4, 6), 256, 0, stream>>>(Wself[0], Wngh[0], Wself[1], Wngh[1],
                                            Wself[2], Wngh[2], wt);

    const int gemm_gx = (N_NODES + 63) / 64;
    const int agg_gx  = (N_NODES + 3) / 4;
    const size_t WSZ = (size_t)D * D;

    // layer 0: hb0 -> hb1 (relu)
    k_gemm<<<dim3(gemm_gx, 2), 256, 0, stream>>>(hb0, wt + 0 * WSZ, wt + 1 * WSZ, bias[0], hs, hn);
    k_agg<<<agg_gx, 256, 0, stream>>>(hs, hn, row_off, csr, rcp, hb1, 0);
    // layer 1: hb1 -> hb0 (relu)
    k_gemm<<<dim3(gemm_gx, 2), 256, 0, stream>>>(hb1, wt + 2 * WSZ, wt + 3 * WSZ, bias[1], hs, hn);
    k_agg<<<agg_gx, 256, 0, stream>>>(hs, hn, row_off, csr, rcp, hb0, 0);
    // layer 2: hb0 -> out (f32, no act)
    k_gemm<<<dim3(gemm_gx, 2), 256, 0, stream>>>(hb0, wt + 4 * WSZ, wt + 5 * WSZ, bias[2], hs, hn);
    k_agg<<<agg_gx, 256, 0, stream>>>(hs, hn, row_off, csr, rcp, out, 1);
}

// Round 9
// 296.884 us; speedup vs baseline: 1.5448x; 1.0886x over previous
//
#include <hip/hip_runtime.h>

#define N_NODES 50000
#define N_EDGES 800000
#define D 128
#define K2 256                         // fused GEMM K dimension
#define NBKT ((N_NODES + 255) / 256)   // 196 buckets of 256 nodes
#define EPB 2048                       // edges per k_part block
#define LDA 136                        // LDS row stride in ushorts (128 + 8 pad)

typedef unsigned short u16;
typedef unsigned int   u32;
typedef short bf16x8 __attribute__((ext_vector_type(8)));
typedef float f32x16 __attribute__((ext_vector_type(16)));

// f32 -> bf16 (round-to-nearest-even)
__device__ __forceinline__ u16 f2b(float x) {
    union { float f; u32 u; } c; c.f = x;
    u32 r = c.u + 0x7FFFu + ((c.u >> 16) & 1u);
    return (u16)(r >> 16);
}
__device__ __forceinline__ float b2f(u16 u) {
    union { u32 u; float f; } c; c.u = ((u32)u) << 16;
    return c.f;
}

// ---------------------------------------------------------------------------
// B1: bucket histogram (bucket = dst>>8). LDS-staged.
// ---------------------------------------------------------------------------
__global__ __launch_bounds__(256) void k_bhist(const int* __restrict__ dst,
                                               int* __restrict__ gbh) {
    __shared__ int h[NBKT];
    for (int t = threadIdx.x; t < NBKT; t += 256) h[t] = 0;
    __syncthreads();
    int base = blockIdx.x * 1024;
#pragma unroll
    for (int j = 0; j < 4; ++j) {
        int e = base + j * 256 + (int)threadIdx.x;
        if (e < N_EDGES) atomicAdd(&h[dst[e] >> 8], 1);
    }
    __syncthreads();
    for (int t = threadIdx.x; t < NBKT; t += 256)
        if (h[t]) atomicAdd(&gbh[t], h[t]);
}

// ---------------------------------------------------------------------------
// B2: scan 196 bucket totals -> bucket_off[NBKT+1]; also row_off[N]=E.
// ---------------------------------------------------------------------------
__global__ __launch_bounds__(256) void k_bscan(const int* __restrict__ gbh,
                                               int* __restrict__ boff,
                                               int* __restrict__ row_off) {
    __shared__ int s[256];
    int v = ((int)threadIdx.x < NBKT) ? gbh[threadIdx.x] : 0;
    s[threadIdx.x] = v;
    __syncthreads();
#pragma unroll
    for (int off = 1; off < 256; off <<= 1) {
        int t = (threadIdx.x >= (unsigned)off) ? s[threadIdx.x - off] : 0;
        __syncthreads();
        s[threadIdx.x] += t;
        __syncthreads();
    }
    if ((int)threadIdx.x < NBKT) boff[threadIdx.x] = s[threadIdx.x] - v;
    if (threadIdx.x == 0) { boff[NBKT] = N_EDGES; row_off[N_NODES] = N_EDGES; }
}

// ---------------------------------------------------------------------------
// B3: partition edges into bucket-contiguous ebuf (chunk reservation).
// ---------------------------------------------------------------------------
__global__ __launch_bounds__(256) void k_part(const int* __restrict__ src,
                                              const int* __restrict__ dst,
                                              const int* __restrict__ boff,
                                              int* __restrict__ gbfill,
                                              u32* __restrict__ ebuf) {
    __shared__ u16 ls[EPB], ld_[EPB];
    __shared__ int hist[NBKT], lcnt[NBKT], basev[NBKT];
    const int e0 = blockIdx.x * EPB;
    for (int t = threadIdx.x; t < NBKT; t += 256) { hist[t] = 0; lcnt[t] = 0; }
    __syncthreads();
#pragma unroll
    for (int j = 0; j < EPB / 256; ++j) {
        int t = j * 256 + (int)threadIdx.x;
        int e = e0 + t;
        if (e < N_EDGES) {
            int d = dst[e];
            ls[t] = (u16)src[e];
            ld_[t] = (u16)d;
            atomicAdd(&hist[d >> 8], 1);
        }
    }
    __syncthreads();
    for (int t = threadIdx.x; t < NBKT; t += 256)
        basev[t] = boff[t] + (hist[t] ? atomicAdd(&gbfill[t], hist[t]) : 0);
    __syncthreads();
#pragma unroll
    for (int j = 0; j < EPB / 256; ++j) {
        int t = j * 256 + (int)threadIdx.x;
        int e = e0 + t;
        if (e < N_EDGES) {
            int d = (int)ld_[t];
            int b = d >> 8;
            int o = atomicAdd(&lcnt[b], 1);
            ebuf[basev[b] + o] = (u32)ls[t] | ((u32)(d & 255) << 16);
        }
    }
}

// ---------------------------------------------------------------------------
// B4: per-bucket build: LDS degree hist + scan -> row_off/rcp, csr fill (u16).
// ---------------------------------------------------------------------------
__global__ __launch_bounds__(256) void k_build(const u32* __restrict__ ebuf,
                                               const int* __restrict__ boff,
                                               int* __restrict__ row_off,
                                               float* __restrict__ rcp,
                                               u16* __restrict__ csr) {
    __shared__ int dcnt[256], fcnt[256], sdata[256];
    const int b = blockIdx.x;
    const int beg = boff[b], end = boff[b + 1];
    dcnt[threadIdx.x] = 0;
    fcnt[threadIdx.x] = 0;
    __syncthreads();
    for (int j = beg + (int)threadIdx.x; j < end; j += 256)
        atomicAdd(&dcnt[(ebuf[j] >> 16) & 255], 1);
    __syncthreads();
    int v = dcnt[threadIdx.x];
    sdata[threadIdx.x] = v;
    __syncthreads();
#pragma unroll
    for (int off = 1; off < 256; off <<= 1) {
        int t = (threadIdx.x >= (unsigned)off) ? sdata[threadIdx.x - off] : 0;
        __syncthreads();
        sdata[threadIdx.x] += t;
        __syncthreads();
    }
    int node = (b << 8) + (int)threadIdx.x;
    if (node < N_NODES) {
        row_off[node] = beg + sdata[threadIdx.x] - v;
        rcp[node] = 1.0f / (float)max(v, 1);
    }
    for (int j = beg + (int)threadIdx.x; j < end; j += 256) {
        u32 u = ebuf[j];
        int ln = (u >> 16) & 255;
        int o = atomicAdd(&fcnt[ln], 1);
        csr[beg + (sdata[ln] - dcnt[ln]) + o] = (u16)(u & 0xFFFFu);
    }
}

// ---------------------------------------------------------------------------
// K4: cast features f32 -> bf16 (8 elems/thread)
// ---------------------------------------------------------------------------
__global__ __launch_bounds__(256) void k_cast(const float* __restrict__ f,
                                              u16* __restrict__ o) {
    int idx = blockIdx.x * 256 + (int)threadIdx.x;
    if (idx < N_NODES * (D / 8)) {
        const float4* fp = (const float4*)(f + (size_t)idx * 8);
        float4 a = fp[0], b = fp[1];
        uint4 p;
        p.x = (u32)f2b(a.x) | ((u32)f2b(a.y) << 16);
        p.y = (u32)f2b(a.z) | ((u32)f2b(a.w) << 16);
        p.z = (u32)f2b(b.x) | ((u32)f2b(b.y) << 16);
        p.w = (u32)f2b(b.z) | ((u32)f2b(b.w) << 16);
        ((uint4*)o)[idx] = p;
    }
}

// ---------------------------------------------------------------------------
// K5: build concatenated transposed weights per layer:
// Wcat[l][n][k], k in [0,256): k<128 from W_self[l], k>=128 from W_neigh[l].
// grid (8, 3): bx = 32-wide k-chunk within 256, by = layer.
// ---------------------------------------------------------------------------
__global__ __launch_bounds__(256) void k_prepw(
        const float* __restrict__ w0, const float* __restrict__ w1,
        const float* __restrict__ w2, const float* __restrict__ w3,
        const float* __restrict__ w4, const float* __restrict__ w5,
        u16* __restrict__ wt) {
    const int idx = (int)blockIdx.y * 2 + ((int)blockIdx.x >= 4 ? 1 : 0);
    const float* W;
    switch (idx) {
        case 0: W = w0; break; case 1: W = w1; break; case 2: W = w2; break;
        case 3: W = w3; break; case 4: W = w4; break; default: W = w5; break;
    }
    u16* out = wt + (size_t)blockIdx.y * D * K2;
    const int k0g = blockIdx.x * 32;        // global k in [0,256)
    const int k0s = k0g & (D - 1);          // source row in [0,128)
    __shared__ float s[32][129];
    for (int t = threadIdx.x; t < 32 * 32; t += 256) {
        int r = t >> 5, c4 = t & 31;
        float4 v = ((const float4*)&W[(size_t)(k0s + r) * D])[c4];
        s[r][c4 * 4 + 0] = v.x; s[r][c4 * 4 + 1] = v.y;
        s[r][c4 * 4 + 2] = v.z; s[r][c4 * 4 + 3] = v.w;
    }
    __syncthreads();
    for (int t = threadIdx.x; t < 512; t += 256) {
        int n = t >> 2, g = t & 3;
        uint4 p;
        p.x = (u32)f2b(s[g * 8 + 0][n]) | ((u32)f2b(s[g * 8 + 1][n]) << 16);
        p.y = (u32)f2b(s[g * 8 + 2][n]) | ((u32)f2b(s[g * 8 + 3][n]) << 16);
        p.z = (u32)f2b(s[g * 8 + 4][n]) | ((u32)f2b(s[g * 8 + 5][n]) << 16);
        p.w = (u32)f2b(s[g * 8 + 6][n]) | ((u32)f2b(s[g * 8 + 7][n]) << 16);
        *(uint4*)&out[(size_t)n * K2 + k0g + g * 8] = p;
    }
}

// ---------------------------------------------------------------------------
// K6: fused-layer MFMA GEMM: out = act( [h|m] @ Wcat + b ), K=256.
// R5 staging/fragment structure, looped over two 128-wide K chunks
// (chunk 0 reads A from h, chunk 1 from m). Block M=64 x N=128, 4 waves 2x2.
// ---------------------------------------------------------------------------
__global__ __launch_bounds__(256) void k_gemm(
        const u16* __restrict__ Ah, const u16* __restrict__ Am,
        const u16* __restrict__ Wt, const float* __restrict__ bias,
        void* __restrict__ outp, int relu, int f32out) {
    const int row0 = blockIdx.x * 64;

    __shared__ u16 As[64 * LDA];    // 17.0 KB
    __shared__ u16 Ws[128 * LDA];   // 34.8 KB

    const int tid  = (int)threadIdx.x;
    const int lane = tid & 63;
    const int wave = tid >> 6;
    const int wm = wave & 1;    // row band (32 rows)
    const int wn = wave >> 1;   // col half (64 cols)
    const int m  = lane & 31;
    const int kh = lane >> 5;   // k-half within 16-chunk

    f32x16 acc0, acc1;
#pragma unroll
    for (int i = 0; i < 16; ++i) { acc0[i] = 0.0f; acc1[i] = 0.0f; }

    const u16* ap  = &As[(wm * 32 + m) * LDA + kh * 8];
    const u16* bp0 = &Ws[(wn * 64 + m) * LDA + kh * 8];
    const u16* bp1 = bp0 + 32 * LDA;

#pragma unroll
    for (int c = 0; c < 2; ++c) {
        const u16* __restrict__ Asrc = c ? Am : Ah;
        const int koff = c * 128;
        if (c) __syncthreads();      // protect LDS reuse across chunks
        // stage A chunk: 64 rows x 128 bf16 = 1024 x 16B
        for (int t = tid; t < 1024; t += 256) {
            int r = t >> 4, cc = t & 15;
            int row = row0 + r; if (row >= N_NODES) row = N_NODES - 1;
            *(float4*)&As[r * LDA + cc * 8] =
                ((const float4*)&Asrc[(size_t)row * D])[cc];
        }
        // stage W chunk: 128 n-rows x 128 bf16 (cols koff..koff+127)
        for (int t = tid; t < 2048; t += 256) {
            int r = t >> 4, cc = t & 15;
            *(float4*)&Ws[r * LDA + cc * 8] =
                *(const float4*)&Wt[(size_t)r * K2 + koff + cc * 8];
        }
        __syncthreads();
#pragma unroll
        for (int kk = 0; kk < 8; ++kk) {
            bf16x8 a  = *(const bf16x8*)(ap  + kk * 16);
            bf16x8 b0 = *(const bf16x8*)(bp0 + kk * 16);
            bf16x8 b1 = *(const bf16x8*)(bp1 + kk * 16);
            acc0 = __builtin_amdgcn_mfma_f32_32x32x16_bf16(a, b0, acc0, 0, 0, 0);
            acc1 = __builtin_amdgcn_mfma_f32_32x32x16_bf16(a, b1, acc1, 0, 0, 0);
        }
    }

    // epilogue: C/D layout: col = lane&31, row = (r&3) + 8*(r>>2) + 4*(lane>>5)
    const int c0 = wn * 64 + m;
    const int c1 = c0 + 32;
    const float b0v = bias[c0];
    const float b1v = bias[c1];
#pragma unroll
    for (int r = 0; r < 16; ++r) {
        int rowl = (r & 3) + 8 * (r >> 2) + 4 * kh;
        int grow = row0 + wm * 32 + rowl;
        if (grow < N_NODES) {
            float o0 = acc0[r] + b0v;
            float o1 = acc1[r] + b1v;
            if (relu) { o0 = fmaxf(o0, 0.0f); o1 = fmaxf(o1, 0.0f); }
            if (f32out) {
                ((float*)outp)[(size_t)grow * D + c0] = o0;
                ((float*)outp)[(size_t)grow * D + c1] = o1;
            } else {
                ((u16*)outp)[(size_t)grow * D + c0] = f2b(o0);
                ((u16*)outp)[(size_t)grow * D + c1] = f2b(o1);
            }
        }
    }
}

// ---------------------------------------------------------------------------
// K7: input-aggregate: m[v] = bf16( rcp[v] * sum_{u in csr(v)} h[u] ).
// One wave/node; quad q handles neighbor j=beg+q (4 nbrs/iter, unroll x2);
// 16 lanes x 16B (8 bf16) per neighbor row. f32 accumulate; shfl-xor reduce.
// ---------------------------------------------------------------------------
__global__ __launch_bounds__(256) void k_aggm(
        const u16* __restrict__ h, const int* __restrict__ row_off,
        const u16* __restrict__ csr, const float* __restrict__ rcp,
        u16* __restrict__ mout) {
    int v = blockIdx.x * 4 + (int)(threadIdx.x >> 6);
    if (v >= N_NODES) return;
    int lane = (int)threadIdx.x & 63;
    int q = lane >> 4, cl = lane & 15;
    int beg = row_off[v], end = row_off[v + 1];

    float ax[8];
#pragma unroll
    for (int i = 0; i < 8; ++i) ax[i] = 0.0f;

    int j = beg + q;
    for (; j + 4 < end; j += 8) {
        int u0 = csr[j], u1 = csr[j + 4];
        bf16x8 x0 = *(const bf16x8*)&h[(size_t)u0 * D + cl * 8];
        bf16x8 x1 = *(const bf16x8*)&h[(size_t)u1 * D + cl * 8];
#pragma unroll
        for (int i = 0; i < 8; ++i)
            ax[i] += b2f((u16)x0[i]) + b2f((u16)x1[i]);
    }
    if (j < end) {
        int u0 = csr[j];
        bf16x8 x0 = *(const bf16x8*)&h[(size_t)u0 * D + cl * 8];
#pragma unroll
        for (int i = 0; i < 8; ++i) ax[i] += b2f((u16)x0[i]);
    }
#pragma unroll
    for (int i = 0; i < 8; ++i) {
        ax[i] += __shfl_xor(ax[i], 16);
        ax[i] += __shfl_xor(ax[i], 32);
    }
    if (lane < 16) {
        float r = rcp[v];
        uint4 p;
        p.x = (u32)f2b(ax[0] * r) | ((u32)f2b(ax[1] * r) << 16);
        p.y = (u32)f2b(ax[2] * r) | ((u32)f2b(ax[3] * r) << 16);
        p.z = (u32)f2b(ax[4] * r) | ((u32)f2b(ax[5] * r) << 16);
        p.w = (u32)f2b(ax[6] * r) | ((u32)f2b(ax[7] * r) << 16);
        *(uint4*)&mout[(size_t)v * D + cl * 8] = p;
    }
}

// ---------------------------------------------------------------------------
extern "C" void kernel_launch(void* const* d_in, const int* in_sizes, int n_in,
                              void* d_out, int out_size, void* d_ws, size_t ws_size,
                              hipStream_t stream) {
    const float* features = (const float*)d_in[0];
    const int*   edge_src = (const int*)d_in[1];
    const int*   edge_dst = (const int*)d_in[2];
    const float* Wself[3] = {(const float*)d_in[3], (const float*)d_in[6], (const float*)d_in[9]};
    const float* Wngh[3]  = {(const float*)d_in[4], (const float*)d_in[7], (const float*)d_in[10]};
    const float* bias[3]  = {(const float*)d_in[5], (const float*)d_in[8], (const float*)d_in[11]};
    float* out = (float*)d_out;

    char* ws = (char*)d_ws;
    size_t off = 0;
    auto alloc = [&](size_t bytes) {
        char* p = ws + off;
        off += (bytes + 255) & ~(size_t)255;
        return p;
    };
    int*   gcnt    = (int*)alloc(2 * 256 * sizeof(int));   // gbh | gbfill
    int*   gbh     = gcnt;
    int*   gbfill  = gcnt + 256;
    int*   boff    = (int*)alloc((NBKT + 1) * sizeof(int));
    int*   row_off = (int*)alloc((N_NODES + 1) * sizeof(int));
    float* rcp     = (float*)alloc(N_NODES * sizeof(float));
    u32*   ebuf    = (u32*)alloc((size_t)N_EDGES * sizeof(u32));
    u16*   csr     = (u16*)alloc((size_t)N_EDGES * sizeof(u16));
    u16*   xa      = (u16*)alloc((size_t)N_NODES * D * sizeof(u16));
    u16*   xb      = (u16*)alloc((size_t)N_NODES * D * sizeof(u16));
    u16*   mb      = (u16*)alloc((size_t)N_NODES * D * sizeof(u16));
    u16*   wt      = (u16*)alloc((size_t)3 * D * K2 * sizeof(u16));

    hipMemsetAsync(gcnt, 0, 2 * 256 * sizeof(int), stream);

    // CSR build (bucketed)
    k_bhist<<<(N_EDGES + 1023) / 1024, 256, 0, stream>>>(edge_dst, gbh);
    k_bscan<<<1, 256, 0, stream>>>(gbh, boff, row_off);
    k_part<<<(N_EDGES + EPB - 1) / EPB, 256, 0, stream>>>(edge_src, edge_dst, boff, gbfill, ebuf);
    k_build<<<NBKT, 256, 0, stream>>>(ebuf, boff, row_off, rcp, csr);

    // bf16 prep
    k_cast<<<(N_NODES * (D / 8) + 255) / 256, 256, 0, stream>>>(features, xa);
    k_prepw<<<dim3(8, 3), 256, 0, stream>>>(Wself[0], Wngh[0], Wself[1], Wngh[1],
                                            Wself[2], Wngh[2], wt);

    const int gemm_gx = (N_NODES + 63) / 64;
    const int agg_gx  = (N_NODES + 3) / 4;
    const size_t WSZ = (size_t)D * K2;

    // layer 0: xa -> xb (relu)
    k_aggm<<<agg_gx, 256, 0, stream>>>(xa, row_off, csr, rcp, mb);
    k_gemm<<<gemm_gx, 256, 0, stream>>>(xa, mb, wt + 0 * WSZ, bias[0], xb, 1, 0);
    // layer 1: xb -> xa (relu)
    k_aggm<<<agg_gx, 256, 0, stream>>>(xb, row_off, csr, rcp, mb);
    k_gemm<<<gemm_gx, 256, 0, stream>>>(xb, mb, wt + 1 * WSZ, bias[1], xa, 1, 0);
    // layer 2: xa -> out (f32, no act)
    k_aggm<<<agg_gx, 256, 0, stream>>>(xa, row_off, csr, rcp, mb);
    k_gemm<<<gemm_gx, 256, 0, stream>>>(xa, mb, wt + 2 * WSZ, bias[2], out, 0, 1);
}

// Round 10
// 276.402 us; speedup vs baseline: 1.6593x; 1.0741x over previous
//
#include <hip/hip_runtime.h>

#define N_NODES 50000
#define N_EDGES 800000
#define D 128
#define K2 256                         // fused GEMM K dimension
#define NBKT ((N_NODES + 255) / 256)   // 196 buckets of 256 nodes
#define BCAP 8192                      // fixed slots per bucket (64 sigma safe)
#define EPB 2048                       // edges per k_part block
#define LDA 136                        // LDS row stride in ushorts (128 + 8 pad)

typedef unsigned short u16;
typedef unsigned int   u32;
typedef short bf16x8 __attribute__((ext_vector_type(8)));
typedef float f32x16 __attribute__((ext_vector_type(16)));

// f32 -> bf16 (round-to-nearest-even)
__device__ __forceinline__ u16 f2b(float x) {
    union { float f; u32 u; } c; c.f = x;
    u32 r = c.u + 0x7FFFu + ((c.u >> 16) & 1u);
    return (u16)(r >> 16);
}
__device__ __forceinline__ float b2f(u16 u) {
    union { u32 u; float f; } c; c.u = ((u32)u) << 16;
    return c.f;
}

// ---------------------------------------------------------------------------
// B1: partition edges into fixed-capacity bucket chunks of ebuf.
// Per-block chunk reservation: one global atomic per bucket per block.
// Record: u32 = src (16b) | local_node (8b) << 16.
// ---------------------------------------------------------------------------
__global__ __launch_bounds__(256) void k_part(const int* __restrict__ src,
                                              const int* __restrict__ dst,
                                              int* __restrict__ gbfill,
                                              u32* __restrict__ ebuf) {
    __shared__ u16 ls[EPB], ld_[EPB];
    __shared__ int hist[NBKT], lcnt[NBKT], basev[NBKT];
    const int e0 = blockIdx.x * EPB;
    for (int t = threadIdx.x; t < NBKT; t += 256) { hist[t] = 0; lcnt[t] = 0; }
    __syncthreads();
#pragma unroll
    for (int j = 0; j < EPB / 256; ++j) {
        int t = j * 256 + (int)threadIdx.x;
        int e = e0 + t;
        if (e < N_EDGES) {
            int d = dst[e];
            ls[t] = (u16)src[e];
            ld_[t] = (u16)d;
            atomicAdd(&hist[d >> 8], 1);
        }
    }
    __syncthreads();
    for (int t = threadIdx.x; t < NBKT; t += 256)
        basev[t] = t * BCAP + (hist[t] ? atomicAdd(&gbfill[t], hist[t]) : 0);
    __syncthreads();
#pragma unroll
    for (int j = 0; j < EPB / 256; ++j) {
        int t = j * 256 + (int)threadIdx.x;
        int e = e0 + t;
        if (e < N_EDGES) {
            int d = (int)ld_[t];
            int b = d >> 8;
            int o = atomicAdd(&lcnt[b], 1);
            ebuf[basev[b] + o] = (u32)ls[t] | ((u32)(d & 255) << 16);
        }
    }
}

// ---------------------------------------------------------------------------
// B2: per-bucket build: LDS degree hist + scan -> row_off/degv/rcp,
// csr fill (u16 src) within the bucket's padded window [b*BCAP, b*BCAP+cnt).
// ---------------------------------------------------------------------------
__global__ __launch_bounds__(256) void k_build(const u32* __restrict__ ebuf,
                                               const int* __restrict__ gbfill,
                                               int* __restrict__ row_off,
                                               u16* __restrict__ degv,
                                               float* __restrict__ rcp,
                                               u16* __restrict__ csr) {
    __shared__ int dcnt[256], fcnt[256], sdata[256];
    const int b = blockIdx.x;
    const int beg = b * BCAP;
    const int end = beg + gbfill[b];
    dcnt[threadIdx.x] = 0;
    fcnt[threadIdx.x] = 0;
    __syncthreads();
    for (int j = beg + (int)threadIdx.x; j < end; j += 256)
        atomicAdd(&dcnt[(ebuf[j] >> 16) & 255], 1);
    __syncthreads();
    int v = dcnt[threadIdx.x];
    sdata[threadIdx.x] = v;
    __syncthreads();
#pragma unroll
    for (int off = 1; off < 256; off <<= 1) {
        int t = (threadIdx.x >= (unsigned)off) ? sdata[threadIdx.x - off] : 0;
        __syncthreads();
        sdata[threadIdx.x] += t;
        __syncthreads();
    }
    int node = (b << 8) + (int)threadIdx.x;
    if (node < N_NODES) {
        row_off[node] = beg + sdata[threadIdx.x] - v;   // exclusive prefix
        degv[node] = (u16)v;
        rcp[node] = 1.0f / (float)max(v, 1);
    }
    for (int j = beg + (int)threadIdx.x; j < end; j += 256) {
        u32 u = ebuf[j];
        int ln = (u >> 16) & 255;
        int o = atomicAdd(&fcnt[ln], 1);
        csr[beg + (sdata[ln] - dcnt[ln]) + o] = (u16)(u & 0xFFFFu);
    }
}

// ---------------------------------------------------------------------------
// K4: cast features f32 -> bf16 (8 elems/thread)
// ---------------------------------------------------------------------------
__global__ __launch_bounds__(256) void k_cast(const float* __restrict__ f,
                                              u16* __restrict__ o) {
    int idx = blockIdx.x * 256 + (int)threadIdx.x;
    if (idx < N_NODES * (D / 8)) {
        const float4* fp = (const float4*)(f + (size_t)idx * 8);
        float4 a = fp[0], b = fp[1];
        uint4 p;
        p.x = (u32)f2b(a.x) | ((u32)f2b(a.y) << 16);
        p.y = (u32)f2b(a.z) | ((u32)f2b(a.w) << 16);
        p.z = (u32)f2b(b.x) | ((u32)f2b(b.y) << 16);
        p.w = (u32)f2b(b.z) | ((u32)f2b(b.w) << 16);
        ((uint4*)o)[idx] = p;
    }
}

// ---------------------------------------------------------------------------
// K5: build concatenated transposed weights per layer:
// Wcat[l][n][k], k in [0,256): k<128 from W_self[l], k>=128 from W_neigh[l].
// grid (8, 3): bx = 32-wide k-chunk within 256, by = layer.
// ---------------------------------------------------------------------------
__global__ __launch_bounds__(256) void k_prepw(
        const float* __restrict__ w0, const float* __restrict__ w1,
        const float* __restrict__ w2, const float* __restrict__ w3,
        const float* __restrict__ w4, const float* __restrict__ w5,
        u16* __restrict__ wt) {
    const int idx = (int)blockIdx.y * 2 + ((int)blockIdx.x >= 4 ? 1 : 0);
    const float* W;
    switch (idx) {
        case 0: W = w0; break; case 1: W = w1; break; case 2: W = w2; break;
        case 3: W = w3; break; case 4: W = w4; break; default: W = w5; break;
    }
    u16* out = wt + (size_t)blockIdx.y * D * K2;
    const int k0g = blockIdx.x * 32;        // global k in [0,256)
    const int k0s = k0g & (D - 1);          // source row in [0,128)
    __shared__ float s[32][129];
    for (int t = threadIdx.x; t < 32 * 32; t += 256) {
        int r = t >> 5, c4 = t & 31;
        float4 v = ((const float4*)&W[(size_t)(k0s + r) * D])[c4];
        s[r][c4 * 4 + 0] = v.x; s[r][c4 * 4 + 1] = v.y;
        s[r][c4 * 4 + 2] = v.z; s[r][c4 * 4 + 3] = v.w;
    }
    __syncthreads();
    for (int t = threadIdx.x; t < 512; t += 256) {
        int n = t >> 2, g = t & 3;
        uint4 p;
        p.x = (u32)f2b(s[g * 8 + 0][n]) | ((u32)f2b(s[g * 8 + 1][n]) << 16);
        p.y = (u32)f2b(s[g * 8 + 2][n]) | ((u32)f2b(s[g * 8 + 3][n]) << 16);
        p.z = (u32)f2b(s[g * 8 + 4][n]) | ((u32)f2b(s[g * 8 + 5][n]) << 16);
        p.w = (u32)f2b(s[g * 8 + 6][n]) | ((u32)f2b(s[g * 8 + 7][n]) << 16);
        *(uint4*)&out[(size_t)n * K2 + k0g + g * 8] = p;
    }
}

// ---------------------------------------------------------------------------
// K6: fused-layer MFMA GEMM: out = act( [h|m] @ Wcat + b ), K=256.
// Block M=64 x N=128, 4 waves 2x2, two 128-wide K chunks through LDS.
// ---------------------------------------------------------------------------
__global__ __launch_bounds__(256) void k_gemm(
        const u16* __restrict__ Ah, const u16* __restrict__ Am,
        const u16* __restrict__ Wt, const float* __restrict__ bias,
        void* __restrict__ outp, int relu, int f32out) {
    const int row0 = blockIdx.x * 64;

    __shared__ u16 As[64 * LDA];    // 17.0 KB
    __shared__ u16 Ws[128 * LDA];   // 34.8 KB

    const int tid  = (int)threadIdx.x;
    const int lane = tid & 63;
    const int wave = tid >> 6;
    const int wm = wave & 1;    // row band (32 rows)
    const int wn = wave >> 1;   // col half (64 cols)
    const int m  = lane & 31;
    const int kh = lane >> 5;   // k-half within 16-chunk

    f32x16 acc0, acc1;
#pragma unroll
    for (int i = 0; i < 16; ++i) { acc0[i] = 0.0f; acc1[i] = 0.0f; }

    const u16* ap  = &As[(wm * 32 + m) * LDA + kh * 8];
    const u16* bp0 = &Ws[(wn * 64 + m) * LDA + kh * 8];
    const u16* bp1 = bp0 + 32 * LDA;

#pragma unroll
    for (int c = 0; c < 2; ++c) {
        const u16* __restrict__ Asrc = c ? Am : Ah;
        const int koff = c * 128;
        if (c) __syncthreads();      // protect LDS reuse across chunks
        // stage A chunk: 64 rows x 128 bf16 = 1024 x 16B
        for (int t = tid; t < 1024; t += 256) {
            int r = t >> 4, cc = t & 15;
            int row = row0 + r; if (row >= N_NODES) row = N_NODES - 1;
            *(float4*)&As[r * LDA + cc * 8] =
                ((const float4*)&Asrc[(size_t)row * D])[cc];
        }
        // stage W chunk: 128 n-rows x 128 bf16 (cols koff..koff+127)
        for (int t = tid; t < 2048; t += 256) {
            int r = t >> 4, cc = t & 15;
            *(float4*)&Ws[r * LDA + cc * 8] =
                *(const float4*)&Wt[(size_t)r * K2 + koff + cc * 8];
        }
        __syncthreads();
#pragma unroll
        for (int kk = 0; kk < 8; ++kk) {
            bf16x8 a  = *(const bf16x8*)(ap  + kk * 16);
            bf16x8 b0 = *(const bf16x8*)(bp0 + kk * 16);
            bf16x8 b1 = *(const bf16x8*)(bp1 + kk * 16);
            acc0 = __builtin_amdgcn_mfma_f32_32x32x16_bf16(a, b0, acc0, 0, 0, 0);
            acc1 = __builtin_amdgcn_mfma_f32_32x32x16_bf16(a, b1, acc1, 0, 0, 0);
        }
    }

    // epilogue: C/D layout: col = lane&31, row = (r&3) + 8*(r>>2) + 4*(lane>>5)
    const int c0 = wn * 64 + m;
    const int c1 = c0 + 32;
    const float b0v = bias[c0];
    const float b1v = bias[c1];
#pragma unroll
    for (int r = 0; r < 16; ++r) {
        int rowl = (r & 3) + 8 * (r >> 2) + 4 * kh;
        int grow = row0 + wm * 32 + rowl;
        if (grow < N_NODES) {
            float o0 = acc0[r] + b0v;
            float o1 = acc1[r] + b1v;
            if (relu) { o0 = fmaxf(o0, 0.0f); o1 = fmaxf(o1, 0.0f); }
            if (f32out) {
                ((float*)outp)[(size_t)grow * D + c0] = o0;
                ((float*)outp)[(size_t)grow * D + c1] = o1;
            } else {
                ((u16*)outp)[(size_t)grow * D + c0] = f2b(o0);
                ((u16*)outp)[(size_t)grow * D + c1] = f2b(o1);
            }
        }
    }
}

// ---------------------------------------------------------------------------
// K7: input-aggregate: m[v] = bf16( rcp[v] * sum_{u in csr(v)} h[u] ).
// One wave/node; quad-group q handles j = beg+q, +4, +8, ... with 4
// independent 256B gathers in flight per main iteration (MLP). 16 lanes x
// 16B per neighbor row. f32 accumulate; shfl-xor cross-group reduce.
// ---------------------------------------------------------------------------
__global__ __launch_bounds__(256) void k_aggm(
        const u16* __restrict__ h, const int* __restrict__ row_off,
        const u16* __restrict__ degv, const u16* __restrict__ csr,
        const float* __restrict__ rcp, u16* __restrict__ mout) {
    int v = blockIdx.x * 4 + (int)(threadIdx.x >> 6);
    if (v >= N_NODES) return;
    int lane = (int)threadIdx.x & 63;
    int q = lane >> 4, cl = lane & 15;
    int beg = row_off[v];
    int end = beg + (int)degv[v];

    float ax[8];
#pragma unroll
    for (int i = 0; i < 8; ++i) ax[i] = 0.0f;

    int j = beg + q;
    for (; j + 12 < end; j += 16) {      // 4 gathers in flight per group
        int u0 = csr[j], u1 = csr[j + 4], u2 = csr[j + 8], u3 = csr[j + 12];
        bf16x8 x0 = *(const bf16x8*)&h[(size_t)u0 * D + cl * 8];
        bf16x8 x1 = *(const bf16x8*)&h[(size_t)u1 * D + cl * 8];
        bf16x8 x2 = *(const bf16x8*)&h[(size_t)u2 * D + cl * 8];
        bf16x8 x3 = *(const bf16x8*)&h[(size_t)u3 * D + cl * 8];
#pragma unroll
        for (int i = 0; i < 8; ++i)
            ax[i] += (b2f((u16)x0[i]) + b2f((u16)x1[i])) +
                     (b2f((u16)x2[i]) + b2f((u16)x3[i]));
    }
    for (; j < end; j += 4) {
        int u0 = csr[j];
        bf16x8 x0 = *(const bf16x8*)&h[(size_t)u0 * D + cl * 8];
#pragma unroll
        for (int i = 0; i < 8; ++i) ax[i] += b2f((u16)x0[i]);
    }
#pragma unroll
    for (int i = 0; i < 8; ++i) {
        ax[i] += __shfl_xor(ax[i], 16);
        ax[i] += __shfl_xor(ax[i], 32);
    }
    if (lane < 16) {
        float r = rcp[v];
        uint4 p;
        p.x = (u32)f2b(ax[0] * r) | ((u32)f2b(ax[1] * r) << 16);
        p.y = (u32)f2b(ax[2] * r) | ((u32)f2b(ax[3] * r) << 16);
        p.z = (u32)f2b(ax[4] * r) | ((u32)f2b(ax[5] * r) << 16);
        p.w = (u32)f2b(ax[6] * r) | ((u32)f2b(ax[7] * r) << 16);
        *(uint4*)&mout[(size_t)v * D + cl * 8] = p;
    }
}

// ---------------------------------------------------------------------------
extern "C" void kernel_launch(void* const* d_in, const int* in_sizes, int n_in,
                              void* d_out, int out_size, void* d_ws, size_t ws_size,
                              hipStream_t stream) {
    const float* features = (const float*)d_in[0];
    const int*   edge_src = (const int*)d_in[1];
    const int*   edge_dst = (const int*)d_in[2];
    const float* Wself[3] = {(const float*)d_in[3], (const float*)d_in[6], (const float*)d_in[9]};
    const float* Wngh[3]  = {(const float*)d_in[4], (const float*)d_in[7], (const float*)d_in[10]};
    const float* bias[3]  = {(const float*)d_in[5], (const float*)d_in[8], (const float*)d_in[11]};
    float* out = (float*)d_out;

    char* ws = (char*)d_ws;
    size_t off = 0;
    auto alloc = [&](size_t bytes) {
        char* p = ws + off;
        off += (bytes + 255) & ~(size_t)255;
        return p;
    };
    int*   gbfill  = (int*)alloc(256 * sizeof(int));
    int*   row_off = (int*)alloc(N_NODES * sizeof(int));
    u16*   degv    = (u16*)alloc(N_NODES * sizeof(u16));
    float* rcp     = (float*)alloc(N_NODES * sizeof(float));
    u32*   ebuf    = (u32*)alloc((size_t)NBKT * BCAP * sizeof(u32));
    u16*   csr     = (u16*)alloc((size_t)NBKT * BCAP * sizeof(u16));
    u16*   xa      = (u16*)alloc((size_t)N_NODES * D * sizeof(u16));
    u16*   xb      = (u16*)alloc((size_t)N_NODES * D * sizeof(u16));
    u16*   mb      = (u16*)alloc((size_t)N_NODES * D * sizeof(u16));
    u16*   wt      = (u16*)alloc((size_t)3 * D * K2 * sizeof(u16));

    hipMemsetAsync(gbfill, 0, 256 * sizeof(int), stream);

    // CSR build (fixed-capacity buckets: no histogram/scan kernels)
    k_part<<<(N_EDGES + EPB - 1) / EPB, 256, 0, stream>>>(edge_src, edge_dst, gbfill, ebuf);
    k_build<<<NBKT, 256, 0, stream>>>(ebuf, gbfill, row_off, degv, rcp, csr);

    // bf16 prep
    k_cast<<<(N_NODES * (D / 8) + 255) / 256, 256, 0, stream>>>(features, xa);
    k_prepw<<<dim3(8, 3), 256, 0, stream>>>(Wself[0], Wngh[0], Wself[1], Wngh[1],
                                            Wself[2], Wngh[2], wt);

    const int gemm_gx = (N_NODES + 63) / 64;
    const int agg_gx  = (N_NODES + 3) / 4;
    const size_t WSZ = (size_t)D * K2;

    // layer 0: xa -> xb (relu)
    k_aggm<<<agg_gx, 256, 0, stream>>>(xa, row_off, degv, csr, rcp, mb);
    k_gemm<<<gemm_gx, 256, 0, stream>>>(xa, mb, wt + 0 * WSZ, bias[0], xb, 1, 0);
    // layer 1: xb -> xa (relu)
    k_aggm<<<agg_gx, 256, 0, stream>>>(xb, row_off, degv, csr, rcp, mb);
    k_gemm<<<gemm_gx, 256, 0, stream>>>(xb, mb, wt + 1 * WSZ, bias[1], xa, 1, 0);
    // layer 2: xa -> out (f32, no act)
    k_aggm<<<agg_gx, 256, 0, stream>>>(xa, row_off, degv, csr, rcp, mb);
    k_gemm<<<gemm_gx, 256, 0, stream>>>(xa, mb, wt + 2 * WSZ, bias[2], out, 0, 1);
}